// Round 7
// baseline (35387.155 us; speedup 1.0000x reference)
//
#include <hip/hip_runtime.h>
#include <hip/hip_bf16.h>
#include <math.h>

#define B_   64
#define T_   256
#define DIN_ 512
#define H_   512
#define D_   1024
#define O_   1536
#define TB_  (T_*B_)
#define EPSf 1e-5f
#define NWG  96          // persistent WGs; WG w owns y-cols [16w,16w+16)

typedef short  bf16x8 __attribute__((ext_vector_type(8)));
typedef float  f32x4  __attribute__((ext_vector_type(4)));
typedef ushort u16x8  __attribute__((ext_vector_type(8)));

#define SPLIT1(f, Hm, Lm) { __hip_bfloat16 _h = __float2bfloat16(f); (Hm) = *(ushort*)&_h; \
    __hip_bfloat16 _l = __float2bfloat16((f) - __bfloat162float(_h)); (Lm) = *(ushort*)&_l; }

// ---------------- fill: Hseq[t][b][d] = d<DIN ? x[b][t][d] : 0 ----------------
__global__ __launch_bounds__(256) void k_fill(const float* __restrict__ x,
                                              float* __restrict__ Hseq) {
    int g  = blockIdx.x * 256 + threadIdx.x;
    int i4 = g * 4;
    int row = i4 / D_;
    int d   = i4 % D_;
    int t = row / B_, b = row % B_;
    float4 v = make_float4(0.f, 0.f, 0.f, 0.f);
    if (d < DIN_) v = *(const float4*)&x[((size_t)b * T_ + t) * DIN_ + d];
    *(float4*)&Hseq[(size_t)i4] = v;
}

// ---------------- mask codes: mcode[t*B+b] = mt | (mn<<1) ----------------
__global__ __launch_bounds__(256) void k_mask(const int* __restrict__ mask,
                                              int* __restrict__ mcode) {
    int g = blockIdx.x * 256 + threadIdx.x;     // t*64+b
    int t = g >> 6, b = g & 63;
    int mt = mask[b * T_ + t] != 0;
    int mn = (t + 1 < T_) ? (mask[b * T_ + t + 1] != 0) : 0;
    mcode[g] = mt | (mn << 1);
}

// ---- transpose + split-bf16: Mt_hi[o][k]+Mt_lo[o][k] ≈ M[k][o]  (M is [D_][O_]) ----
__global__ __launch_bounds__(256) void k_prep(const float* __restrict__ M,
                                              __hip_bfloat16* __restrict__ Mt_hi,
                                              __hip_bfloat16* __restrict__ Mt_lo) {
    __shared__ float ls[64][65];
    int k0 = blockIdx.y * 64;
    int o0 = blockIdx.x * 64;
    int tid = threadIdx.x;
    int r = tid >> 2, cq = tid & 3;
#pragma unroll
    for (int j = 0; j < 4; ++j) {
        float4 v = *(const float4*)&M[(size_t)(k0 + r) * O_ + o0 + cq * 16 + j * 4];
        ls[r][cq * 16 + j * 4 + 0] = v.x;
        ls[r][cq * 16 + j * 4 + 1] = v.y;
        ls[r][cq * 16 + j * 4 + 2] = v.z;
        ls[r][cq * 16 + j * 4 + 3] = v.w;
    }
    __syncthreads();
    int ol = tid >> 2, kq = tid & 3;
    ushort th[16], tl[16];
#pragma unroll
    for (int j = 0; j < 16; ++j) {
        float v = ls[kq * 16 + j][ol];
        SPLIT1(v, th[j], tl[j]);
    }
    size_t base = (size_t)(o0 + ol) * D_ + k0 + kq * 16;
    *(int4*)&Mt_hi[base]     = *(int4*)&th[0];
    *(int4*)&Mt_hi[base + 8] = *(int4*)&th[8];
    *(int4*)&Mt_lo[base]     = *(int4*)&tl[0];
    *(int4*)&Mt_lo[base + 8] = *(int4*)&tl[8];
}

// -------- split-bf16 MFMA GEMM: C[M,O_] = A[M,D_] @ W  (W given as Wt[o][k] hi/lo) ----
__global__ __launch_bounds__(256) void k_gemmb(const float* __restrict__ A,
                                               const __hip_bfloat16* __restrict__ Bh,
                                               const __hip_bfloat16* __restrict__ Bl,
                                               float* __restrict__ C) {
    __shared__ __hip_bfloat16 sAh[128 * 40];
    __shared__ __hip_bfloat16 sAl[128 * 40];
    __shared__ __hip_bfloat16 sBh[128 * 40];
    __shared__ __hip_bfloat16 sBl[128 * 40];
    const int tid = threadIdx.x;
    const int row0 = blockIdx.y * 128, col0 = blockIdx.x * 128;
    const int lane = tid & 63, wv = tid >> 6;
    const int lr = lane & 15, lg = lane >> 4;
    const int wr = wv >> 1, wc = wv & 1;
    const int sr = tid & 127, sh = (tid >> 7) * 16;
    f32x4 acc[4][4] = {};
    for (int k0 = 0; k0 < D_; k0 += 32) {
        const float* ap = A + (size_t)(row0 + sr) * D_ + k0 + sh;
        float4 a0 = *(const float4*)ap;
        float4 a1 = *(const float4*)(ap + 4);
        float4 a2 = *(const float4*)(ap + 8);
        float4 a3 = *(const float4*)(ap + 12);
        u16x8 h0, h1, l0, l1;
        SPLIT1(a0.x, h0[0], l0[0]); SPLIT1(a0.y, h0[1], l0[1]);
        SPLIT1(a0.z, h0[2], l0[2]); SPLIT1(a0.w, h0[3], l0[3]);
        SPLIT1(a1.x, h0[4], l0[4]); SPLIT1(a1.y, h0[5], l0[5]);
        SPLIT1(a1.z, h0[6], l0[6]); SPLIT1(a1.w, h0[7], l0[7]);
        SPLIT1(a2.x, h1[0], l1[0]); SPLIT1(a2.y, h1[1], l1[1]);
        SPLIT1(a2.z, h1[2], l1[2]); SPLIT1(a2.w, h1[3], l1[3]);
        SPLIT1(a3.x, h1[4], l1[4]); SPLIT1(a3.y, h1[5], l1[5]);
        SPLIT1(a3.z, h1[6], l1[6]); SPLIT1(a3.w, h1[7], l1[7]);
        *(u16x8*)&sAh[sr * 40 + sh]     = h0;
        *(u16x8*)&sAh[sr * 40 + sh + 8] = h1;
        *(u16x8*)&sAl[sr * 40 + sh]     = l0;
        *(u16x8*)&sAl[sr * 40 + sh + 8] = l1;
        const __hip_bfloat16* bph = Bh + (size_t)(col0 + sr) * D_ + k0 + sh;
        const __hip_bfloat16* bpl = Bl + (size_t)(col0 + sr) * D_ + k0 + sh;
        *(int4*)&sBh[sr * 40 + sh]     = *(const int4*)bph;
        *(int4*)&sBh[sr * 40 + sh + 8] = *(const int4*)(bph + 8);
        *(int4*)&sBl[sr * 40 + sh]     = *(const int4*)bpl;
        *(int4*)&sBl[sr * 40 + sh + 8] = *(const int4*)(bpl + 8);
        __syncthreads();
        bf16x8 vbh[4], vbl[4];
#pragma unroll
        for (int ni = 0; ni < 4; ++ni) {
            int cb = (wc * 64 + ni * 16 + lr) * 40 + lg * 8;
            vbh[ni] = *(const bf16x8*)&sBh[cb];
            vbl[ni] = *(const bf16x8*)&sBl[cb];
        }
#pragma unroll
        for (int mi = 0; mi < 4; ++mi) {
            int rb = (wr * 64 + mi * 16 + lr) * 40 + lg * 8;
            bf16x8 vah = *(const bf16x8*)&sAh[rb];
            bf16x8 val = *(const bf16x8*)&sAl[rb];
#pragma unroll
            for (int ni = 0; ni < 4; ++ni) {
                acc[mi][ni] = __builtin_amdgcn_mfma_f32_16x16x32_bf16(vah, vbh[ni], acc[mi][ni], 0, 0, 0);
                acc[mi][ni] = __builtin_amdgcn_mfma_f32_16x16x32_bf16(vah, vbl[ni], acc[mi][ni], 0, 0, 0);
                acc[mi][ni] = __builtin_amdgcn_mfma_f32_16x16x32_bf16(val, vbh[ni], acc[mi][ni], 0, 0, 0);
            }
        }
        __syncthreads();
    }
#pragma unroll
    for (int mi = 0; mi < 4; ++mi)
#pragma unroll
        for (int ni = 0; ni < 4; ++ni)
#pragma unroll
            for (int jj = 0; jj < 4; ++jj) {
                int r = row0 + wr * 64 + mi * 16 + lg * 4 + jj;
                int c = col0 + wc * 64 + ni * 16 + lr;
                C[(size_t)r * O_ + c] = acc[mi][ni][jj];
            }
}

// ---------------- in-place row LayerNorm + bias ----------------
__global__ __launch_bounds__(256) void k_ln_bias(float* __restrict__ S,
                                                 const float* __restrict__ gamma,
                                                 const float* __restrict__ beta,
                                                 const float* __restrict__ bias) {
    size_t row = blockIdx.x;
    float v[6];
    float s = 0.f, s2 = 0.f;
#pragma unroll
    for (int j = 0; j < 6; ++j) {
        v[j] = S[row * O_ + j * 256 + threadIdx.x];
        s += v[j]; s2 += v[j] * v[j];
    }
    for (int off = 32; off; off >>= 1) { s += __shfl_down(s, off); s2 += __shfl_down(s2, off); }
    __shared__ float red[8];
    int wid = threadIdx.x / 64, lane = threadIdx.x % 64;
    if (lane == 0) { red[wid] = s; red[4 + wid] = s2; }
    __syncthreads();
    float ts = red[0] + red[1] + red[2] + red[3];
    float t2 = red[4] + red[5] + red[6] + red[7];
    float mean = ts * (1.f / O_);
    float var  = t2 * (1.f / O_) - mean * mean;
    float inv  = 1.f / (sqrtf(var + EPSf) + EPSf);
#pragma unroll
    for (int j = 0; j < 6; ++j) {
        int o = j * 256 + threadIdx.x;
        S[row * O_ + o] = gamma[o] * (v[j] - mean) * inv + beta[o] + bias[o];
    }
}

// ------ group barrier: relaxed spin, single release/acquire fences ------
__device__ inline void gbar(unsigned* __restrict__ flags, int w, unsigned bar) {
    __syncthreads();
    __builtin_amdgcn_fence(__ATOMIC_RELEASE, "agent");   // waitcnt + L2 writeback (once)
    if (threadIdx.x == 0)
        __hip_atomic_store(&flags[w], bar, __ATOMIC_RELAXED, __HIP_MEMORY_SCOPE_AGENT);
    if (threadIdx.x < NWG) {
        while (__hip_atomic_load(&flags[threadIdx.x], __ATOMIC_RELAXED,
                                 __HIP_MEMORY_SCOPE_AGENT) < bar)
            __builtin_amdgcn_s_sleep(2);
    }
    __syncthreads();
    __builtin_amdgcn_fence(__ATOMIC_ACQUIRE, "agent");   // L1/L2 invalidate (once)
}

// -------- persistent per-layer recurrence (register-resident gating) --------
__global__ __launch_bounds__(256) void k_recur(
        float* __restrict__ Hseq, float* __restrict__ FKseq,
        const float* __restrict__ S1, float* __restrict__ Y,
        float* __restrict__ pstats, unsigned* __restrict__ flags,
        const __hip_bfloat16* __restrict__ Ut_hi,
        const __hip_bfloat16* __restrict__ Ut_lo,
        __hip_bfloat16* __restrict__ Hb_hi, __hip_bfloat16* __restrict__ Hb_lo,
        const float* __restrict__ g1, const float* __restrict__ be1,
        const int* __restrict__ mcode) {
    __shared__ __hip_bfloat16 uls_hi[16 * 1024];   // U tile [c][k], XOR-swizzled
    __shared__ __hip_bfloat16 uls_lo[16 * 1024];
    const int w = blockIdx.x;
    const int tid = threadIdx.x;
    const int lane = tid & 63;
    const int wv = tid >> 6;
    const int lr = lane & 15;
    const int lg = lane >> 4;
    const int c0 = w * 16;
    const int b0 = wv * 16;

    // load U tiles into LDS once (swizzled: byte ^= (col&7)<<4)
    {
        int cl = tid >> 4;
        int kc = tid & 15;
        const __hip_bfloat16* sh = Ut_hi + (size_t)(c0 + cl) * D_ + kc * 64;
        const __hip_bfloat16* sl = Ut_lo + (size_t)(c0 + cl) * D_ + kc * 64;
        char* bh = (char*)uls_hi;
        char* bl = (char*)uls_lo;
#pragma unroll
        for (int j = 0; j < 8; ++j) {
            int k = kc * 64 + j * 8;
            int off = (cl * 2048 + k * 2) ^ ((cl & 7) << 4);
            *(int4*)(bh + off) = *(const int4*)(sh + j * 8);
            *(int4*)(bl + off) = *(const int4*)(sl + j * 8);
        }
    }
    __syncthreads();

    const int d = c0 + lr;
    const bool gate_wg = (w < 64);
    const bool tanh_wg = (w >= 32 && w < 64);
    float g1d = 0.f, be1d = 0.f, g1e = 0.f, be1e = 0.f;
    if (gate_wg) { g1d = g1[d]; be1d = be1[d]; }
    if (tanh_wg) { g1e = g1[d + 512]; be1e = be1[d + 512]; }
    int brow[4];
#pragma unroll
    for (int j = 0; j < 4; ++j) brow[j] = b0 + lg * 4 + j;
    float h1r[4]  = {0.f, 0.f, 0.f, 0.f};
    float fk1r[4] = {0.f, 0.f, 0.f, 0.f};

    unsigned bar = 0;
    for (int t = 0; t < T_; ++t) {
        // ---- prefetch gating inputs into registers ----
        float s1d[4], s1e[4], xtv[4], fkpv[4];
        int mc[4];
        if (gate_wg) {
#pragma unroll
            for (int j = 0; j < 4; ++j) {
                size_t row = (size_t)t * B_ + brow[j];
                s1d[j]  = S1[row * O_ + d];
                xtv[j]  = Hseq[row * D_ + d];
                fkpv[j] = (t + 1 < T_) ? FKseq[(row + B_) * D_ + d] : 0.f;
                mc[j]   = mcode[t * B_ + brow[j]];
                if (tanh_wg) s1e[j] = S1[row * O_ + d + 512];
            }
        }
        // ---- phase 1: y tile = h_tm1 @ U via 3 independent MFMA chains ----
        f32x4 ac0 = {0.f, 0.f, 0.f, 0.f};
        f32x4 ac1 = {0.f, 0.f, 0.f, 0.f};
        f32x4 ac2 = {0.f, 0.f, 0.f, 0.f};
        {
            const __hip_bfloat16* AH = Hb_hi + (size_t)(b0 + lr) * D_;
            const __hip_bfloat16* AL = Hb_lo + (size_t)(b0 + lr) * D_;
            const char* bhb = (const char*)uls_hi;
            const char* blb = (const char*)uls_lo;
#pragma unroll 8
            for (int kc = 0; kc < 32; ++kc) {
                int k = kc * 32 + lg * 8;
                int off = (lr * 2048 + k * 2) ^ ((lr & 7) << 4);
                bf16x8 ah = *(const bf16x8*)(AH + k);
                bf16x8 al = *(const bf16x8*)(AL + k);
                bf16x8 bh = *(const bf16x8*)(bhb + off);
                bf16x8 bl = *(const bf16x8*)(blb + off);
                ac0 = __builtin_amdgcn_mfma_f32_16x16x32_bf16(ah, bh, ac0, 0, 0, 0);
                ac1 = __builtin_amdgcn_mfma_f32_16x16x32_bf16(ah, bl, ac1, 0, 0, 0);
                ac2 = __builtin_amdgcn_mfma_f32_16x16x32_bf16(al, bh, ac2, 0, 0, 0);
            }
        }
        f32x4 acc = ac0 + ac1 + ac2;
        // tanh-source cols go to memory (consumed by WGs w-32)
        if (w >= 64) {
#pragma unroll
            for (int j = 0; j < 4; ++j)
                Y[(size_t)brow[j] * O_ + c0 + lr] = acc[j];
        }
        // per-row partial stats
#pragma unroll
        for (int j = 0; j < 4; ++j) {
            float s = acc[j], q = acc[j] * acc[j];
#pragma unroll
            for (int m = 1; m < 16; m <<= 1) { s += __shfl_xor(s, m); q += __shfl_xor(q, m); }
            if (lr == 0)
                *(float2*)&pstats[((size_t)brow[j] * NWG + w) * 2] = make_float2(s, q);
        }
        gbar(flags, w, ++bar);

        // ---- phase 2: stats gather (own rows only) + register gating ----
        if (gate_wg) {
            float ye[4];
            if (tanh_wg) {
#pragma unroll
                for (int j = 0; j < 4; ++j)
                    ye[j] = Y[(size_t)brow[j] * O_ + d + 512];
            }
            int rl = lane >> 2, q4 = lane & 3;
            const float* pp = &pstats[((size_t)(b0 + rl) * NWG + q4 * 24) * 2];
            float s = 0.f, q2 = 0.f;
#pragma unroll
            for (int i = 0; i < 12; ++i) {
                float4 v = *(const float4*)(pp + i * 4);
                s += v.x + v.z; q2 += v.y + v.w;
            }
            s  += __shfl_xor(s, 1);  s  += __shfl_xor(s, 2);
            q2 += __shfl_xor(q2, 1); q2 += __shfl_xor(q2, 2);
#pragma unroll
            for (int j = 0; j < 4; ++j) {
                int src = (lg * 4 + j) * 4;
                float ts = __shfl(s, src);
                float tq = __shfl(q2, src);
                float mean = ts * (1.f / O_);
                float var  = tq * (1.f / O_) - mean * mean;
                float inv  = 1.f / (sqrtf(var + EPSf) + EPSf);
                float td  = s1d[j] + g1d * (acc[j] - mean) * inv + be1d;
                float fkc = fminf(fmaxf(0.2f * td + 0.5f, 0.f), 1.f);
                float hpad = 0.f;
                if (tanh_wg) {
                    float te = s1e[j] + g1e * (ye[j] - mean) * inv + be1e;
                    hpad = tanhf(te);
                }
                float hc = (1.f - fkc) * xtv[j] + fkc * hpad;
                float h  = fkpv[j] * h1r[j] + (1.f - fkpv[j]) * hc;
                float fk = fkpv[j] + (1.f - fkpv[j]) * fkc;
                int mt = mc[j] & 1, mn = (mc[j] >> 1) & 1;
                if (mt && !mn) fk = 0.f;
                float oh  = mt ? h  : h1r[j];
                float ofk = mt ? fk : fk1r[j];
                h1r[j] = oh; fk1r[j] = ofk;
                size_t row = (size_t)t * B_ + brow[j];
                Hseq[row * D_ + d]  = oh;
                FKseq[row * D_ + d] = ofk;
                __hip_bfloat16 hh = __float2bfloat16(oh);
                Hb_hi[(size_t)brow[j] * D_ + d] = hh;
                Hb_lo[(size_t)brow[j] * D_ + d] = __float2bfloat16(oh - __bfloat162float(hh));
            }
        }
        gbar(flags, w, ++bar);
    }
}

// ---------------- output ----------------
__global__ __launch_bounds__(256) void k_out(const float* __restrict__ Hseq,
                                             float* __restrict__ out) {
    int g = blockIdx.x * 256 + threadIdx.x;
    int b = g >> 9, j = g & 511;
    out[g] = Hseq[((size_t)255 * B_ + b) * D_ + 512 + j];
}

extern "C" void kernel_launch(void* const* d_in, const int* in_sizes, int n_in,
                              void* d_out, int out_size, void* d_ws, size_t ws_size,
                              hipStream_t stream) {
    (void)in_sizes; (void)n_in; (void)out_size;
    const float* x      = (const float*)d_in[0];
    const int*   mask   = (const int*)d_in[1];
    const float* W      = (const float*)d_in[2];
    const float* U      = (const float*)d_in[3];
    const float* bias   = (const float*)d_in[4];
    const float* gammas = (const float*)d_in[5];
    const float* betas  = (const float*)d_in[6];

    float* ws     = (float*)d_ws;
    float* Hseq   = ws;                                    // TB_*D_
    float* FKseq  = Hseq  + (size_t)TB_ * D_;              // TB_*D_
    float* S1     = FKseq + (size_t)TB_ * D_;              // TB_*O_
    float* Y      = S1    + (size_t)TB_ * O_;              // B_*O_
    float* pstats = Y     + (size_t)B_ * O_;               // B_*NWG*2
    unsigned* flags = (unsigned*)(pstats + (size_t)B_ * NWG * 2);  // 128
    __hip_bfloat16* Hb_hi = (__hip_bfloat16*)(flags + 128);        // B_*D_
    __hip_bfloat16* Hb_lo = Hb_hi + (size_t)B_ * D_;               // B_*D_
    __hip_bfloat16* Ut_hi = Hb_lo + (size_t)B_ * D_;               // O_*D_
    __hip_bfloat16* Ut_lo = Ut_hi + (size_t)O_ * D_;               // O_*D_
    __hip_bfloat16* Wt_hi = Ut_lo + (size_t)O_ * D_;               // O_*D_
    __hip_bfloat16* Wt_lo = Wt_hi + (size_t)O_ * D_;               // O_*D_
    int* mcode = (int*)(Wt_lo + (size_t)O_ * D_);                  // TB_
    size_t need_bytes = ((size_t)TB_ * D_ * 2 + (size_t)TB_ * O_ +
                         (size_t)B_ * O_ + (size_t)B_ * NWG * 2) * 4 + 128 * 4 +
                        ((size_t)B_ * D_ * 2 + (size_t)O_ * D_ * 4) * 2 +
                        (size_t)TB_ * 4;
    if (ws_size < need_bytes) return;

    (void)hipMemsetAsync(FKseq, 0, sizeof(float) * (size_t)TB_ * D_, stream);
    k_fill<<<TB_ * D_ / 4 / 256, 256, 0, stream>>>(x, Hseq);
    k_mask<<<TB_ / 256, 256, 0, stream>>>(mask, mcode);
    k_prep<<<dim3(O_ / 64, D_ / 64), 256, 0, stream>>>(U, Ut_hi, Ut_lo);
    k_prep<<<dim3(O_ / 64, D_ / 64), 256, 0, stream>>>(W, Wt_hi, Wt_lo);

    const float* g0  = gammas;       const float* g1  = gammas + O_;
    const float* be0 = betas;        const float* be1 = betas + O_;

    for (int layer = 0; layer < 4; ++layer) {
        k_gemmb<<<dim3(O_ / 128, TB_ / 128), 256, 0, stream>>>(Hseq, Wt_hi, Wt_lo, S1);
        k_ln_bias<<<TB_, 256, 0, stream>>>(S1, g0, be0, bias);
        (void)hipMemsetAsync(flags, 0, sizeof(unsigned) * NWG, stream);
        (void)hipMemsetAsync(Hb_hi, 0, sizeof(__hip_bfloat16) * (size_t)B_ * D_ * 2, stream);
        k_recur<<<NWG, 256, 0, stream>>>(Hseq, FKseq, S1, Y, pstats, flags,
                                         Ut_hi, Ut_lo, Hb_hi, Hb_lo, g1, be1, mcode);
    }
    k_out<<<(B_ * 512) / 256, 256, 0, stream>>>(Hseq, (float*)d_out);
}

// Round 8
// 23659.822 us; speedup vs baseline: 1.4957x; 1.4957x over previous
//
#include <hip/hip_runtime.h>
#include <hip/hip_bf16.h>
#include <math.h>

#define B_   64
#define T_   256
#define DIN_ 512
#define H_   512
#define D_   1024
#define O_   1536
#define TB_  (T_*B_)
#define EPSf 1e-5f
#define NWG  96          // persistent WGs; WG w owns y-cols [16w,16w+16)

typedef short  bf16x8 __attribute__((ext_vector_type(8)));
typedef float  f32x4  __attribute__((ext_vector_type(4)));
typedef ushort u16x8  __attribute__((ext_vector_type(8)));

#define SPLIT1(f, Hm, Lm) { __hip_bfloat16 _h = __float2bfloat16(f); (Hm) = *(ushort*)&_h; \
    __hip_bfloat16 _l = __float2bfloat16((f) - __bfloat162float(_h)); (Lm) = *(ushort*)&_l; }

// coherent (device-scope, IC-direct) store/load helpers
__device__ inline void st_f32_coh(float* p, float v) {
    __hip_atomic_store(p, v, __ATOMIC_RELAXED, __HIP_MEMORY_SCOPE_AGENT);
}
__device__ inline void st_u16_coh(ushort* p, ushort v) {
    __hip_atomic_store(p, v, __ATOMIC_RELAXED, __HIP_MEMORY_SCOPE_AGENT);
}
__device__ inline void st_f32x2_coh(float* p, float a, float b) {
    union { float f[2]; unsigned long long u; } pk;
    pk.f[0] = a; pk.f[1] = b;
    __hip_atomic_store((unsigned long long*)p, pk.u, __ATOMIC_RELAXED,
                       __HIP_MEMORY_SCOPE_AGENT);
}

// ---------------- fill: Hseq[t][b][d] = d<DIN ? x[b][t][d] : 0 ----------------
__global__ __launch_bounds__(256) void k_fill(const float* __restrict__ x,
                                              float* __restrict__ Hseq) {
    int g  = blockIdx.x * 256 + threadIdx.x;
    int i4 = g * 4;
    int row = i4 / D_;
    int d   = i4 % D_;
    int t = row / B_, b = row % B_;
    float4 v = make_float4(0.f, 0.f, 0.f, 0.f);
    if (d < DIN_) v = *(const float4*)&x[((size_t)b * T_ + t) * DIN_ + d];
    *(float4*)&Hseq[(size_t)i4] = v;
}

// ---------------- mask codes: mcode[t*B+b] = mt | (mn<<1) ----------------
__global__ __launch_bounds__(256) void k_mask(const int* __restrict__ mask,
                                              int* __restrict__ mcode) {
    int g = blockIdx.x * 256 + threadIdx.x;     // t*64+b
    int t = g >> 6, b = g & 63;
    int mt = mask[b * T_ + t] != 0;
    int mn = (t + 1 < T_) ? (mask[b * T_ + t + 1] != 0) : 0;
    mcode[g] = mt | (mn << 1);
}

// ---- transpose + split-bf16: Mt_hi[o][k]+Mt_lo[o][k] ≈ M[k][o]  (M is [D_][O_]) ----
__global__ __launch_bounds__(256) void k_prep(const float* __restrict__ M,
                                              __hip_bfloat16* __restrict__ Mt_hi,
                                              __hip_bfloat16* __restrict__ Mt_lo) {
    __shared__ float ls[64][65];
    int k0 = blockIdx.y * 64;
    int o0 = blockIdx.x * 64;
    int tid = threadIdx.x;
    int r = tid >> 2, cq = tid & 3;
#pragma unroll
    for (int j = 0; j < 4; ++j) {
        float4 v = *(const float4*)&M[(size_t)(k0 + r) * O_ + o0 + cq * 16 + j * 4];
        ls[r][cq * 16 + j * 4 + 0] = v.x;
        ls[r][cq * 16 + j * 4 + 1] = v.y;
        ls[r][cq * 16 + j * 4 + 2] = v.z;
        ls[r][cq * 16 + j * 4 + 3] = v.w;
    }
    __syncthreads();
    int ol = tid >> 2, kq = tid & 3;
    ushort th[16], tl[16];
#pragma unroll
    for (int j = 0; j < 16; ++j) {
        float v = ls[kq * 16 + j][ol];
        SPLIT1(v, th[j], tl[j]);
    }
    size_t base = (size_t)(o0 + ol) * D_ + k0 + kq * 16;
    *(int4*)&Mt_hi[base]     = *(int4*)&th[0];
    *(int4*)&Mt_hi[base + 8] = *(int4*)&th[8];
    *(int4*)&Mt_lo[base]     = *(int4*)&tl[0];
    *(int4*)&Mt_lo[base + 8] = *(int4*)&tl[8];
}

// -------- split-bf16 MFMA GEMM: C[M,O_] = A[M,D_] @ W  (W given as Wt[o][k] hi/lo) ----
__global__ __launch_bounds__(256) void k_gemmb(const float* __restrict__ A,
                                               const __hip_bfloat16* __restrict__ Bh,
                                               const __hip_bfloat16* __restrict__ Bl,
                                               float* __restrict__ C) {
    __shared__ __hip_bfloat16 sAh[128 * 40];
    __shared__ __hip_bfloat16 sAl[128 * 40];
    __shared__ __hip_bfloat16 sBh[128 * 40];
    __shared__ __hip_bfloat16 sBl[128 * 40];
    const int tid = threadIdx.x;
    const int row0 = blockIdx.y * 128, col0 = blockIdx.x * 128;
    const int lane = tid & 63, wv = tid >> 6;
    const int lr = lane & 15, lg = lane >> 4;
    const int wr = wv >> 1, wc = wv & 1;
    const int sr = tid & 127, sh = (tid >> 7) * 16;
    f32x4 acc[4][4] = {};
    for (int k0 = 0; k0 < D_; k0 += 32) {
        const float* ap = A + (size_t)(row0 + sr) * D_ + k0 + sh;
        float4 a0 = *(const float4*)ap;
        float4 a1 = *(const float4*)(ap + 4);
        float4 a2 = *(const float4*)(ap + 8);
        float4 a3 = *(const float4*)(ap + 12);
        u16x8 h0, h1, l0, l1;
        SPLIT1(a0.x, h0[0], l0[0]); SPLIT1(a0.y, h0[1], l0[1]);
        SPLIT1(a0.z, h0[2], l0[2]); SPLIT1(a0.w, h0[3], l0[3]);
        SPLIT1(a1.x, h0[4], l0[4]); SPLIT1(a1.y, h0[5], l0[5]);
        SPLIT1(a1.z, h0[6], l0[6]); SPLIT1(a1.w, h0[7], l0[7]);
        SPLIT1(a2.x, h1[0], l1[0]); SPLIT1(a2.y, h1[1], l1[1]);
        SPLIT1(a2.z, h1[2], l1[2]); SPLIT1(a2.w, h1[3], l1[3]);
        SPLIT1(a3.x, h1[4], l1[4]); SPLIT1(a3.y, h1[5], l1[5]);
        SPLIT1(a3.z, h1[6], l1[6]); SPLIT1(a3.w, h1[7], l1[7]);
        *(u16x8*)&sAh[sr * 40 + sh]     = h0;
        *(u16x8*)&sAh[sr * 40 + sh + 8] = h1;
        *(u16x8*)&sAl[sr * 40 + sh]     = l0;
        *(u16x8*)&sAl[sr * 40 + sh + 8] = l1;
        const __hip_bfloat16* bph = Bh + (size_t)(col0 + sr) * D_ + k0 + sh;
        const __hip_bfloat16* bpl = Bl + (size_t)(col0 + sr) * D_ + k0 + sh;
        *(int4*)&sBh[sr * 40 + sh]     = *(const int4*)bph;
        *(int4*)&sBh[sr * 40 + sh + 8] = *(const int4*)(bph + 8);
        *(int4*)&sBl[sr * 40 + sh]     = *(const int4*)bpl;
        *(int4*)&sBl[sr * 40 + sh + 8] = *(const int4*)(bpl + 8);
        __syncthreads();
        bf16x8 vbh[4], vbl[4];
#pragma unroll
        for (int ni = 0; ni < 4; ++ni) {
            int cb = (wc * 64 + ni * 16 + lr) * 40 + lg * 8;
            vbh[ni] = *(const bf16x8*)&sBh[cb];
            vbl[ni] = *(const bf16x8*)&sBl[cb];
        }
#pragma unroll
        for (int mi = 0; mi < 4; ++mi) {
            int rb = (wr * 64 + mi * 16 + lr) * 40 + lg * 8;
            bf16x8 vah = *(const bf16x8*)&sAh[rb];
            bf16x8 val = *(const bf16x8*)&sAl[rb];
#pragma unroll
            for (int ni = 0; ni < 4; ++ni) {
                acc[mi][ni] = __builtin_amdgcn_mfma_f32_16x16x32_bf16(vah, vbh[ni], acc[mi][ni], 0, 0, 0);
                acc[mi][ni] = __builtin_amdgcn_mfma_f32_16x16x32_bf16(vah, vbl[ni], acc[mi][ni], 0, 0, 0);
                acc[mi][ni] = __builtin_amdgcn_mfma_f32_16x16x32_bf16(val, vbh[ni], acc[mi][ni], 0, 0, 0);
            }
        }
        __syncthreads();
    }
#pragma unroll
    for (int mi = 0; mi < 4; ++mi)
#pragma unroll
        for (int ni = 0; ni < 4; ++ni)
#pragma unroll
            for (int jj = 0; jj < 4; ++jj) {
                int r = row0 + wr * 64 + mi * 16 + lg * 4 + jj;
                int c = col0 + wc * 64 + ni * 16 + lr;
                C[(size_t)r * O_ + c] = acc[mi][ni][jj];
            }
}

// ---------------- in-place row LayerNorm + bias ----------------
__global__ __launch_bounds__(256) void k_ln_bias(float* __restrict__ S,
                                                 const float* __restrict__ gamma,
                                                 const float* __restrict__ beta,
                                                 const float* __restrict__ bias) {
    size_t row = blockIdx.x;
    float v[6];
    float s = 0.f, s2 = 0.f;
#pragma unroll
    for (int j = 0; j < 6; ++j) {
        v[j] = S[row * O_ + j * 256 + threadIdx.x];
        s += v[j]; s2 += v[j] * v[j];
    }
    for (int off = 32; off; off >>= 1) { s += __shfl_down(s, off); s2 += __shfl_down(s2, off); }
    __shared__ float red[8];
    int wid = threadIdx.x / 64, lane = threadIdx.x % 64;
    if (lane == 0) { red[wid] = s; red[4 + wid] = s2; }
    __syncthreads();
    float ts = red[0] + red[1] + red[2] + red[3];
    float t2 = red[4] + red[5] + red[6] + red[7];
    float mean = ts * (1.f / O_);
    float var  = t2 * (1.f / O_) - mean * mean;
    float inv  = 1.f / (sqrtf(var + EPSf) + EPSf);
#pragma unroll
    for (int j = 0; j < 6; ++j) {
        int o = j * 256 + threadIdx.x;
        S[row * O_ + o] = gamma[o] * (v[j] - mean) * inv + beta[o] + bias[o];
    }
}

// ------ group barrier: sc1-store protocol --------------------------------
// All intra-kernel shared data is written with coherent (agent-relaxed) stores,
// so release = s_waitcnt vmcnt(0) only (NO buffer_wbl2). Readers use plain
// cached loads; the single acquire fence (buffer_inv) after the barrier makes
// the XCD L2 refetch fresh lines from the IC (keeping intra-XCD sharing).
__device__ inline void gbar(unsigned* __restrict__ flags, int w, unsigned bar) {
    __syncthreads();
    asm volatile("s_waitcnt vmcnt(0)" ::: "memory");     // sc1 stores visible device-wide
    if (threadIdx.x == 0)
        __hip_atomic_store(&flags[w], bar, __ATOMIC_RELAXED, __HIP_MEMORY_SCOPE_AGENT);
    if (threadIdx.x < NWG) {
        while (__hip_atomic_load(&flags[threadIdx.x], __ATOMIC_RELAXED,
                                 __HIP_MEMORY_SCOPE_AGENT) < bar)
            __builtin_amdgcn_s_sleep(2);
    }
    __syncthreads();
    __builtin_amdgcn_fence(__ATOMIC_ACQUIRE, "agent");   // one buffer_inv
}

// -------- persistent per-layer recurrence (register-resident gating) --------
__global__ __launch_bounds__(256) void k_recur(
        float* __restrict__ Hseq, float* __restrict__ FKseq,
        const float* __restrict__ S1, float* __restrict__ Y,
        float* __restrict__ pstats, unsigned* __restrict__ flags,
        const __hip_bfloat16* __restrict__ Ut_hi,
        const __hip_bfloat16* __restrict__ Ut_lo,
        __hip_bfloat16* __restrict__ Hb_hi, __hip_bfloat16* __restrict__ Hb_lo,
        const float* __restrict__ g1, const float* __restrict__ be1,
        const int* __restrict__ mcode) {
    __shared__ __hip_bfloat16 uls_hi[16 * 1024];   // U tile [c][k], XOR-swizzled
    __shared__ __hip_bfloat16 uls_lo[16 * 1024];
    const int w = blockIdx.x;
    const int tid = threadIdx.x;
    const int lane = tid & 63;
    const int wv = tid >> 6;
    const int lr = lane & 15;
    const int lg = lane >> 4;
    const int c0 = w * 16;
    const int b0 = wv * 16;

    // load U tiles into LDS once (swizzled: byte ^= (col&7)<<4)
    {
        int cl = tid >> 4;
        int kc = tid & 15;
        const __hip_bfloat16* sh = Ut_hi + (size_t)(c0 + cl) * D_ + kc * 64;
        const __hip_bfloat16* sl = Ut_lo + (size_t)(c0 + cl) * D_ + kc * 64;
        char* bh = (char*)uls_hi;
        char* bl = (char*)uls_lo;
#pragma unroll
        for (int j = 0; j < 8; ++j) {
            int k = kc * 64 + j * 8;
            int off = (cl * 2048 + k * 2) ^ ((cl & 7) << 4);
            *(int4*)(bh + off) = *(const int4*)(sh + j * 8);
            *(int4*)(bl + off) = *(const int4*)(sl + j * 8);
        }
    }
    __syncthreads();

    const int d = c0 + lr;
    const bool gate_wg = (w < 64);
    const bool tanh_wg = (w >= 32 && w < 64);
    float g1d = 0.f, be1d = 0.f, g1e = 0.f, be1e = 0.f;
    if (gate_wg) { g1d = g1[d]; be1d = be1[d]; }
    if (tanh_wg) { g1e = g1[d + 512]; be1e = be1[d + 512]; }
    int brow[4];
#pragma unroll
    for (int j = 0; j < 4; ++j) brow[j] = b0 + lg * 4 + j;
    float h1r[4]  = {0.f, 0.f, 0.f, 0.f};
    float fk1r[4] = {0.f, 0.f, 0.f, 0.f};

    unsigned bar = 0;
    for (int t = 0; t < T_; ++t) {
        // ---- prefetch gating inputs into registers ----
        float s1d[4], s1e[4], xtv[4], fkpv[4];
        int mc[4];
        if (gate_wg) {
#pragma unroll
            for (int j = 0; j < 4; ++j) {
                size_t row = (size_t)t * B_ + brow[j];
                s1d[j]  = S1[row * O_ + d];
                xtv[j]  = Hseq[row * D_ + d];
                fkpv[j] = (t + 1 < T_) ? FKseq[(row + B_) * D_ + d] : 0.f;
                mc[j]   = mcode[t * B_ + brow[j]];
                if (tanh_wg) s1e[j] = S1[row * O_ + d + 512];
            }
        }
        // ---- phase 1: y tile = h_tm1 @ U via 3 independent MFMA chains ----
        f32x4 ac0 = {0.f, 0.f, 0.f, 0.f};
        f32x4 ac1 = {0.f, 0.f, 0.f, 0.f};
        f32x4 ac2 = {0.f, 0.f, 0.f, 0.f};
        {
            const __hip_bfloat16* AH = Hb_hi + (size_t)(b0 + lr) * D_;
            const __hip_bfloat16* AL = Hb_lo + (size_t)(b0 + lr) * D_;
            const char* bhb = (const char*)uls_hi;
            const char* blb = (const char*)uls_lo;
#pragma unroll 8
            for (int kc = 0; kc < 32; ++kc) {
                int k = kc * 32 + lg * 8;
                int off = (lr * 2048 + k * 2) ^ ((lr & 7) << 4);
                bf16x8 ah = *(const bf16x8*)(AH + k);
                bf16x8 al = *(const bf16x8*)(AL + k);
                bf16x8 bh = *(const bf16x8*)(bhb + off);
                bf16x8 bl = *(const bf16x8*)(blb + off);
                ac0 = __builtin_amdgcn_mfma_f32_16x16x32_bf16(ah, bh, ac0, 0, 0, 0);
                ac1 = __builtin_amdgcn_mfma_f32_16x16x32_bf16(ah, bl, ac1, 0, 0, 0);
                ac2 = __builtin_amdgcn_mfma_f32_16x16x32_bf16(al, bh, ac2, 0, 0, 0);
            }
        }
        f32x4 acc = ac0 + ac1 + ac2;
        // tanh-source cols go to IC (consumed by WGs w-32)
        if (w >= 64) {
#pragma unroll
            for (int j = 0; j < 4; ++j)
                st_f32_coh(&Y[(size_t)brow[j] * O_ + c0 + lr], acc[j]);
        }
        // per-row partial stats -> IC
#pragma unroll
        for (int j = 0; j < 4; ++j) {
            float s = acc[j], q = acc[j] * acc[j];
#pragma unroll
            for (int m = 1; m < 16; m <<= 1) { s += __shfl_xor(s, m); q += __shfl_xor(q, m); }
            if (lr == 0)
                st_f32x2_coh(&pstats[((size_t)brow[j] * NWG + w) * 2], s, q);
        }
        gbar(flags, w, ++bar);

        // ---- phase 2: stats gather (own rows only) + register gating ----
        if (gate_wg) {
            float ye[4];
            if (tanh_wg) {
#pragma unroll
                for (int j = 0; j < 4; ++j)
                    ye[j] = Y[(size_t)brow[j] * O_ + d + 512];
            }
            int rl = lane >> 2, q4 = lane & 3;
            const float* pp = &pstats[((size_t)(b0 + rl) * NWG + q4 * 24) * 2];
            float s = 0.f, q2 = 0.f;
#pragma unroll
            for (int i = 0; i < 12; ++i) {
                float4 v = *(const float4*)(pp + i * 4);
                s += v.x + v.z; q2 += v.y + v.w;
            }
            s  += __shfl_xor(s, 1);  s  += __shfl_xor(s, 2);
            q2 += __shfl_xor(q2, 1); q2 += __shfl_xor(q2, 2);
#pragma unroll
            for (int j = 0; j < 4; ++j) {
                int src = (lg * 4 + j) * 4;
                float ts = __shfl(s, src);
                float tq = __shfl(q2, src);
                float mean = ts * (1.f / O_);
                float var  = tq * (1.f / O_) - mean * mean;
                float inv  = 1.f / (sqrtf(var + EPSf) + EPSf);
                float td  = s1d[j] + g1d * (acc[j] - mean) * inv + be1d;
                float fkc = fminf(fmaxf(0.2f * td + 0.5f, 0.f), 1.f);
                float hpad = 0.f;
                if (tanh_wg) {
                    float te = s1e[j] + g1e * (ye[j] - mean) * inv + be1e;
                    hpad = tanhf(te);
                }
                float hc = (1.f - fkc) * xtv[j] + fkc * hpad;
                float h  = fkpv[j] * h1r[j] + (1.f - fkpv[j]) * hc;
                float fk = fkpv[j] + (1.f - fkpv[j]) * fkc;
                int mt = mc[j] & 1, mn = (mc[j] >> 1) & 1;
                if (mt && !mn) fk = 0.f;
                float oh  = mt ? h  : h1r[j];
                float ofk = mt ? fk : fk1r[j];
                h1r[j] = oh; fk1r[j] = ofk;
                size_t row = (size_t)t * B_ + brow[j];
                Hseq[row * D_ + d]  = oh;        // cross-kernel only: plain store
                FKseq[row * D_ + d] = ofk;       // cross-kernel only: plain store
                __hip_bfloat16 hh = __float2bfloat16(oh);
                float lo = oh - __bfloat162float(hh);
                __hip_bfloat16 hl = __float2bfloat16(lo);
                st_u16_coh((ushort*)&Hb_hi[(size_t)brow[j] * D_ + d], *(ushort*)&hh);
                st_u16_coh((ushort*)&Hb_lo[(size_t)brow[j] * D_ + d], *(ushort*)&hl);
            }
        }
        gbar(flags, w, ++bar);
    }
}

// ---------------- output ----------------
__global__ __launch_bounds__(256) void k_out(const float* __restrict__ Hseq,
                                             float* __restrict__ out) {
    int g = blockIdx.x * 256 + threadIdx.x;
    int b = g >> 9, j = g & 511;
    out[g] = Hseq[((size_t)255 * B_ + b) * D_ + 512 + j];
}

extern "C" void kernel_launch(void* const* d_in, const int* in_sizes, int n_in,
                              void* d_out, int out_size, void* d_ws, size_t ws_size,
                              hipStream_t stream) {
    (void)in_sizes; (void)n_in; (void)out_size;
    const float* x      = (const float*)d_in[0];
    const int*   mask   = (const int*)d_in[1];
    const float* W      = (const float*)d_in[2];
    const float* U      = (const float*)d_in[3];
    const float* bias   = (const float*)d_in[4];
    const float* gammas = (const float*)d_in[5];
    const float* betas  = (const float*)d_in[6];

    float* ws     = (float*)d_ws;
    float* Hseq   = ws;                                    // TB_*D_
    float* FKseq  = Hseq  + (size_t)TB_ * D_;              // TB_*D_
    float* S1     = FKseq + (size_t)TB_ * D_;              // TB_*O_
    float* Y      = S1    + (size_t)TB_ * O_;              // B_*O_
    float* pstats = Y     + (size_t)B_ * O_;               // B_*NWG*2
    unsigned* flags = (unsigned*)(pstats + (size_t)B_ * NWG * 2);  // 128
    __hip_bfloat16* Hb_hi = (__hip_bfloat16*)(flags + 128);        // B_*D_
    __hip_bfloat16* Hb_lo = Hb_hi + (size_t)B_ * D_;               // B_*D_
    __hip_bfloat16* Ut_hi = Hb_lo + (size_t)B_ * D_;               // O_*D_
    __hip_bfloat16* Ut_lo = Ut_hi + (size_t)O_ * D_;               // O_*D_
    __hip_bfloat16* Wt_hi = Ut_lo + (size_t)O_ * D_;               // O_*D_
    __hip_bfloat16* Wt_lo = Wt_hi + (size_t)O_ * D_;               // O_*D_
    int* mcode = (int*)(Wt_lo + (size_t)O_ * D_);                  // TB_
    size_t need_bytes = ((size_t)TB_ * D_ * 2 + (size_t)TB_ * O_ +
                         (size_t)B_ * O_ + (size_t)B_ * NWG * 2) * 4 + 128 * 4 +
                        ((size_t)B_ * D_ * 2 + (size_t)O_ * D_ * 4) * 2 +
                        (size_t)TB_ * 4;
    if (ws_size < need_bytes) return;

    (void)hipMemsetAsync(FKseq, 0, sizeof(float) * (size_t)TB_ * D_, stream);
    k_fill<<<TB_ * D_ / 4 / 256, 256, 0, stream>>>(x, Hseq);
    k_mask<<<TB_ / 256, 256, 0, stream>>>(mask, mcode);
    k_prep<<<dim3(O_ / 64, D_ / 64), 256, 0, stream>>>(U, Ut_hi, Ut_lo);
    k_prep<<<dim3(O_ / 64, D_ / 64), 256, 0, stream>>>(W, Wt_hi, Wt_lo);

    const float* g0  = gammas;       const float* g1  = gammas + O_;
    const float* be0 = betas;        const float* be1 = betas + O_;

    for (int layer = 0; layer < 4; ++layer) {
        k_gemmb<<<dim3(O_ / 128, TB_ / 128), 256, 0, stream>>>(Hseq, Wt_hi, Wt_lo, S1);
        k_ln_bias<<<TB_, 256, 0, stream>>>(S1, g0, be0, bias);
        (void)hipMemsetAsync(flags, 0, sizeof(unsigned) * NWG, stream);
        (void)hipMemsetAsync(Hb_hi, 0, sizeof(__hip_bfloat16) * (size_t)B_ * D_ * 2, stream);
        k_recur<<<NWG, 256, 0, stream>>>(Hseq, FKseq, S1, Y, pstats, flags,
                                         Ut_hi, Ut_lo, Hb_hi, Hb_lo, g1, be1, mcode);
    }
    k_out<<<(B_ * 512) / 256, 256, 0, stream>>>(Hseq, (float*)d_out);
}